// Round 7
// baseline (269.700 us; speedup 1.0000x reference)
//
#include <hip/hip_runtime.h>
#include <math.h>

#define Bv   64
#define Nv   900
#define Mv   64
#define NCls 128
#define NCOLS (Nv + 1)          // 901 columns incl. dummy col 0
#define KREG 15                 // columns per lane: j = t + 64k, k=0..14
#define INFV 1000000000.0f
#define BIGV 1.0e18f            // sentinel for used/invalid slots

// uniform dynamic read of a constant-indexed register array (serial chain;
// used only in the rare backtrack)
#define SEL15(arr, kidx, dst) do {            \
    int _s = arr[0];                          \
    _Pragma("unroll")                         \
    for (int _kk = 1; _kk < KREG; _kk++)      \
        _s = ((kidx) == _kk) ? arr[_kk] : _s; \
    (dst) = _s;                               \
} while (0)

// binary-tree select (depth 4, 14 selects) for the hot p-lookup; kidx uniform
#define SELTREE15(arr, kidx, dst) do {                      \
    int _a0 = ((kidx) & 1) ? arr[1]  : arr[0];              \
    int _a1 = ((kidx) & 1) ? arr[3]  : arr[2];              \
    int _a2 = ((kidx) & 1) ? arr[5]  : arr[4];              \
    int _a3 = ((kidx) & 1) ? arr[7]  : arr[6];              \
    int _a4 = ((kidx) & 1) ? arr[9]  : arr[8];              \
    int _a5 = ((kidx) & 1) ? arr[11] : arr[10];             \
    int _a6 = ((kidx) & 1) ? arr[13] : arr[12];             \
    int _a7 = arr[14];          /* k==15 never occurs */    \
    int _b0 = ((kidx) & 2) ? _a1 : _a0;                     \
    int _b1 = ((kidx) & 2) ? _a3 : _a2;                     \
    int _b2 = ((kidx) & 2) ? _a5 : _a4;                     \
    int _b3 = ((kidx) & 2) ? _a7 : _a6;                     \
    int _c0 = ((kidx) & 4) ? _b1 : _b0;                     \
    int _c1 = ((kidx) & 4) ? _b3 : _b2;                     \
    (dst)   = ((kidx) & 8) ? _c1 : _c0;                     \
} while (0)

// uniform dynamic write (lane-targeted)
#define SET15(arr, kidx, val) do {            \
    _Pragma("unroll")                         \
    for (int _kk = 0; _kk < KREG; _kk++)      \
        if ((kidx) == _kk) arr[_kk] = (val);  \
} while (0)

// ---- order-preserving float <-> sortable u32 (bit-exact round trip) --------
__device__ __forceinline__ unsigned f2s(float f) {
    unsigned x = __float_as_uint(f);
    return x ^ ((unsigned)((int)x >> 31) | 0x80000000u);
}
__device__ __forceinline__ float s2f(unsigned s) {
    unsigned x = ((int)s < 0) ? (s ^ 0x80000000u) : ~s;
    return __uint_as_float(x);
}

// ---- wave64 min-reduce of packed (hi=sortable value, lo=index) via DPP -----
// HW-verified R4/R5. Lexicographic (value, index) == first-index argmin.
__device__ __forceinline__ void wave_min_pair(unsigned& hi, unsigned& lo) {
#define DPP_STEP(ctrl, rmask)                                                   \
    {                                                                           \
        unsigned ohi = (unsigned)__builtin_amdgcn_update_dpp(                   \
            (int)hi, (int)hi, ctrl, rmask, 0xf, false);                         \
        unsigned olo = (unsigned)__builtin_amdgcn_update_dpp(                   \
            (int)lo, (int)lo, ctrl, rmask, 0xf, false);                         \
        bool take = (ohi < hi) || (ohi == hi && olo < lo);                      \
        hi = take ? ohi : hi;                                                   \
        lo = take ? olo : lo;                                                   \
    }
    DPP_STEP(0x111, 0xf)   // row_shr:1
    DPP_STEP(0x112, 0xf)   // row_shr:2
    DPP_STEP(0x114, 0xf)   // row_shr:4
    DPP_STEP(0x118, 0xf)   // row_shr:8
    DPP_STEP(0x142, 0xa)   // row_bcast:15
    DPP_STEP(0x143, 0xc)   // row_bcast:31 -> lane 63 holds min
#undef DPP_STEP
    hi = (unsigned)__builtin_amdgcn_readlane((int)hi, 63);
    lo = (unsigned)__builtin_amdgcn_readlane((int)lo, 63);
}

__device__ __forceinline__ float wave_sum_f32(float x) {
#define SSTEP(ctrl, rmask)                                                \
    {                                                                     \
        int o = __builtin_amdgcn_update_dpp(0, __float_as_int(x),         \
                                            ctrl, rmask, 0xf, false);     \
        x += __int_as_float(o);                                           \
    }
    SSTEP(0x111, 0xf) SSTEP(0x112, 0xf) SSTEP(0x114, 0xf) SSTEP(0x118, 0xf)
    SSTEP(0x142, 0xa) SSTEP(0x143, 0xc)
#undef SSTEP
    return __int_as_float(__builtin_amdgcn_readlane(__float_as_int(x), 63));
}

// ---------------------------------------------------------------------------
// Kernel 1: cost matrix. 4 waves/block, one n per wave (verified R6).
// ---------------------------------------------------------------------------
__global__ __launch_bounds__(256) void cost_kernel(
    const float* __restrict__ logits,   // [B,N,128]
    const float* __restrict__ corners,  // [B,N,8,3]
    const int*   __restrict__ labels,   // [B,64]
    const float* __restrict__ boxes,    // [B,64,7]
    float*       __restrict__ C)        // [B,N,64]
{
    const int b = blockIdx.y;
    const int n = blockIdx.x * 4 + (threadIdx.x >> 6);
    const int t = threadIdx.x & 63;
    const long bn = (long)b * Nv + n;

    const float2 l2 = ((const float2*)(logits + bn * NCls))[t];
    const float* cp = corners + bn * 24;
    float cx = 0.f, cy = 0.f, cz = 0.f;
    if (t < 8) { cx = cp[3 * t]; cy = cp[3 * t + 1]; cz = cp[3 * t + 2]; }
    const int    lbl = labels[b * Mv + t];
    const float* bx  = boxes + ((long)b * Mv + t) * 7;
    const float bx0 = bx[0], bx1 = bx[1], bx2 = bx[2];

    float e0 = expf(l2.x), e1 = expf(l2.y);
    float s  = wave_sum_f32(e0 + e1);

    cx = wave_sum_f32(cx) * 0.125f;
    cy = wave_sum_f32(cy) * 0.125f;
    cz = wave_sum_f32(cz) * 0.125f;

    float p0 = __shfl(e0, lbl >> 1, 64);
    float p1 = __shfl(e1, lbl >> 1, 64);
    float pm = ((lbl & 1) ? p1 : p0) / s;

    float dx = cx - bx0, dy = cy - bx1, dz = cz - bx2;
    C[bn * Mv + t] = 5.0f * sqrtf(dx * dx + dy * dy + dz * dz) - pm;
}

// ---------------------------------------------------------------------------
// Kernel 2: LAPJV-style LSA, one wave per batch. R6 verified structure
// (gather layout, DPP reduce, sentinel masking, prefetch). R7: absolute-
// distance (Delta-form) Dijkstra — eliminates the per-iteration
// v/minv/u update pass entirely:
//   D[j] = minv[j] + Delta stays FIXED once improved; Delta accumulates.
//   scan: ca = crow2[k] + h, h = Delta - u[i0]  (v pre-folded at prefetch:
//         v only changes for used slots, which are BIGV-masked).
//   v settlement deferred: v[j] -= Delta_final - Delta_sel(j)  (vsel recorded
//         at selection). u settlement deferred: u[row] += Delta_final - uin
//         (uin = Delta when row discovered; every row scans with its
//         pre-phase u, matching the reference's update order).
// Exact-arithmetic-identical to the reference recursion; float rounding
// differs by ~ulp (same accepted risk class as the greedy Phase A/B init).
// Plus: SELTREE15 p-lookup (depth 4 vs 14), single packed-pair DPP reduce.
// ---------------------------------------------------------------------------
__global__ __launch_bounds__(64) void lsa_kernel(
    const float* __restrict__ C,    // [B, N, M] = [64,900,64]
    float* __restrict__ outPred, float* __restrict__ outTgt)
{
    const int b = blockIdx.x;
    const int t = threadIdx.x;
    const float* cb = C + (size_t)b * Nv * Mv;

    // ---- Phase A: row argmin (lane t = row t+1); 4 ranges, deep unroll
    float mv0 = INFV, mv1 = INFV, mv2 = INFV, mv3 = INFV;
    int   mj0 = 0,    mj1 = 0,    mj2 = 0,    mj3 = 0;
    #pragma unroll 9
    for (int n = 0; n < 225; ++n) {
        float c0 = cb[(size_t)(n      ) * Mv + t];
        float c1 = cb[(size_t)(n + 225) * Mv + t];
        float c2 = cb[(size_t)(n + 450) * Mv + t];
        float c3 = cb[(size_t)(n + 675) * Mv + t];
        if (c0 < mv0) { mv0 = c0; mj0 = n;       }
        if (c1 < mv1) { mv1 = c1; mj1 = n + 225; }
        if (c2 < mv2) { mv2 = c2; mj2 = n + 450; }
        if (c3 < mv3) { mv3 = c3; mj3 = n + 675; }
    }
    float rowmin = mv0; int rown = mj0;
    if (mv1 < rowmin) { rowmin = mv1; rown = mj1; }
    if (mv2 < rowmin) { rowmin = mv2; rown = mj2; }
    if (mv3 < rowmin) { rowmin = mv3; rown = mj3; }

    float u_reg = rowmin;            // lane l holds u[l+1]
    const int jcol = rown + 1;       // column index in 1..900

    // ---- Phase B: duplicate detection (first occurrence wins)
    bool isdup = false;
    #pragma unroll
    for (int s = 1; s < 64; ++s) {
        int oj = __shfl(jcol, (t + 64 - s) & 63, 64);
        isdup |= (oj == jcol) && (s <= t);
    }
    unsigned long long pending = __ballot(isdup);

    int   p_reg[KREG], way_reg[KREG];
    float v_reg[KREG], D[KREG], crow[KREG], vsel[KREG];
    #pragma unroll
    for (int k = 0; k < KREG; k++) { p_reg[k] = 0; way_reg[k] = 0; v_reg[k] = 0.f; }

    int rowcol = isdup ? 0 : jcol;   // lane i: column assigned to row i+1

    // scatter winners into distributed p[]
    #pragma unroll 8
    for (int i = 0; i < 64; ++i) {
        int jb = __shfl(jcol, i, 64);
        if (!((pending >> i) & 1ull) && t == (jb & 63))
            SET15(p_reg, jb >> 6, i + 1);
    }

    // ---- Phase C: Dijkstra phases for conflicted rows only
    while (pending) {
        const int i1v = __ffsll(pending);    // 1-based free row
        pending &= pending - 1;

        unsigned usedMask = (t == 0) ? 1u : 0u;   // dummy col 0 used
        #pragma unroll
        for (int k = 0; k < KREG; k++) { D[k] = INFV; vsel[k] = 0.f; }
        float uin  = (t == i1v - 1) ? 0.0f : -1.0f;  // Delta at row discovery
        float dCur = 0.0f;                           // accumulated Delta
        float dF   = 0.0f;                           // final Delta

        int j0 = 0;
        int i0 = i1v;

        // initial gather for row i0 (v pre-folded; used/invalid -> BIGV)
        {
            const int src0 = __builtin_amdgcn_readfirstlane(i0 - 1);
            #pragma unroll
            for (int k = 0; k < KREG; k++) {
                int j = t + (k << 6);
                bool valid = (j >= 1 && j < NCOLS) && !((usedMask >> k) & 1u);
                crow[k] = valid
                          ? cb[(((size_t)(j - 1)) << 6) + src0] - v_reg[k] : BIGV;
            }
        }

        while (true) {
            const int sl = __builtin_amdgcn_readfirstlane(i0 - 1);
            const float u_i0 = __int_as_float(
                __builtin_amdgcn_readlane(__float_as_int(u_reg), sl));
            const float h = dCur - u_i0;

            // scan: D[k] = min(D[k], crow2[k] + h); 3-way split argmin track
            float bv0 = INFV, bv1 = INFV, bv2 = INFV;
            int   bk0 = 0,    bk1 = 5,    bk2 = 10;
            #pragma unroll
            for (int k = 0; k < 5; k++) {
                float ca = crow[k] + h;
                bool lt = ca < D[k];
                if (lt) { D[k] = ca; way_reg[k] = j0; }
                if (D[k] < bv0) { bv0 = D[k]; bk0 = k; }
            }
            #pragma unroll
            for (int k = 5; k < 10; k++) {
                float ca = crow[k] + h;
                bool lt = ca < D[k];
                if (lt) { D[k] = ca; way_reg[k] = j0; }
                if (D[k] < bv1) { bv1 = D[k]; bk1 = k; }
            }
            #pragma unroll
            for (int k = 10; k < KREG; k++) {
                float ca = crow[k] + h;
                bool lt = ca < D[k];
                if (lt) { D[k] = ca; way_reg[k] = j0; }
                if (D[k] < bv2) { bv2 = D[k]; bk2 = k; }
            }
            if (bv1 < bv0) { bv0 = bv1; bk0 = bk1; }   // strict: earlier range
            if (bv2 < bv0) { bv0 = bv2; bk0 = bk2; }   //  wins ties (first-j)

            unsigned hi = f2s(bv0), lo = (unsigned)(t + (bk0 << 6));
            wave_min_pair(hi, lo);
            const float dNew = s2f(hi);      // new absolute Delta
            const int   j1   = (int)lo;

            const int k1 = j1 >> 6, l1 = j1 & 63;   // uniform (SGPR)
            int ptmp; SELTREE15(p_reg, k1, ptmp);
            const int inext = __builtin_amdgcn_readlane(ptmp, l1);

            // issue next row's loads ASAP (latency hides under bookkeeping)
            float pf[KREG];
            if (inext != 0) {
                const int src = __builtin_amdgcn_readfirstlane(inext - 1);
                #pragma unroll
                for (int k = 0; k < KREG; k++) {
                    int j = t + (k << 6);
                    pf[k] = (j >= 1 && j < NCOLS)
                            ? cb[(((size_t)(j - 1)) << 6) + src] : BIGV;
                }
            }

            // mark selected col: exclude from future mins, record Delta_sel
            const bool newbit = (t == l1);
            #pragma unroll
            for (int k = 0; k < KREG; k++) {
                if (newbit && (k == k1)) { D[k] = BIGV; vsel[k] = dNew; }
            }
            usedMask |= newbit ? (1u << k1) : 0u;
            // record Delta at discovery of row inext
            if (t == inext - 1) uin = dNew;

            dCur = dNew;
            j0 = j1;
            i0 = inext;
            if (i0 == 0) { dF = dNew; break; }   // free column reached

            // fold used-mask + v into the prefetched row
            #pragma unroll
            for (int k = 0; k < KREG; k++) {
                bool used = (usedMask >> k) & 1u;
                crow[k] = used ? BIGV : pf[k] - v_reg[k];
            }
        }

        // settle duals (deferred updates)
        if (uin >= 0.0f) u_reg += (dF - uin);
        #pragma unroll
        for (int k = 0; k < KREG; k++) {
            if ((usedMask >> k) & 1u) v_reg[k] -= (dF - vsel[k]);
        }

        // backtrack: reassign columns along augmenting path
        while (j0 != 0) {
            const int k0 = j0 >> 6, l0 = j0 & 63;
            int wtmp; SEL15(way_reg, k0, wtmp);
            const int jprev = __shfl(wtmp, l0, 64);
            int pv;
            if (jprev == 0) {
                pv = i1v;
            } else {
                int ptmp2; SEL15(p_reg, jprev >> 6, ptmp2);
                pv = __shfl(ptmp2, jprev & 63, 64);
            }
            if (t == l0) SET15(p_reg, k0, pv);
            if (t == pv - 1) rowcol = j0;    // maintain row->column mirror
            j0 = jprev;
        }
    }

    outPred[b * Mv + t] = (float)(rowcol - 1);
    outTgt[b * Mv + t]  = (float)t;
}

// ---------------------------------------------------------------------------
extern "C" void kernel_launch(void* const* d_in, const int* in_sizes, int n_in,
                              void* d_out, int out_size, void* d_ws, size_t ws_size,
                              hipStream_t stream)
{
    (void)in_sizes; (void)n_in; (void)out_size; (void)d_ws; (void)ws_size;

    const float* logits  = (const float*)d_in[0];   // [64,900,128] f32
    const float* corners = (const float*)d_in[1];   // [64,900,8,3] f32
    const int*   labels  = (const int*)  d_in[2];   // [64,64] i32
    const float* boxes   = (const float*)d_in[3];   // [64,64,7] f32

    float* out  = (float*)d_out;
    float* Cc   = out;                               // [64,900,64]
    float* pred = out + (size_t)Bv * Nv * Mv;        // [64,64] as f32
    float* tgt  = pred + (size_t)Bv * Mv;            // [64,64] as f32

    cost_kernel<<<dim3(225, Bv), 256, 0, stream>>>(logits, corners, labels, boxes, Cc);
    lsa_kernel<<<Bv, 64, 0, stream>>>(Cc, pred, tgt);
}